// Round 1
// 438.376 us; speedup vs baseline: 1.1139x; 1.1139x over previous
//
#include <hip/hip_runtime.h>

typedef __attribute__((ext_vector_type(4))) float f32x4;
typedef __attribute__((ext_vector_type(8))) short bf16x8;

#define EPS_ 1e-5f
// SCALE * log2(e): fold exp -> exp2 into the q scaling
#define QSC 0.25503639409729144f

// Dynamic LDS layout (ushort units):
// X/obuf  [64][264]            @0      (16896 us)  rows 528B: bank stride 4 -> 2-way, free
// chunks  8 x 7424             @16896  (59392 us)
//   per-wave chunk: q[64][40] @0, k[64][40] @2560 (P[64][72] overlays q+k), vT[32][72] @5120
// tok_off int[64]              @76288us (byte 152576)
#define XS 264
#define SCB 16896
#define CHUNK 7424
#define QSTR 40
#define KOFF 2560
#define PSTR 72
#define VTOFF 5120
#define VSTR 72
#define LDS_US 76288
#define LDS_BYTES (LDS_US * 2 + 256)

__device__ __forceinline__ unsigned int pack2(float a, float b) {
  union { float f; unsigned int u; } ua, ub;
  ua.f = a; ub.f = b;
  unsigned int ra = (ua.u + 0x7FFFu + ((ua.u >> 16) & 1u)) >> 16;
  unsigned int rb = (ub.u + 0x7FFFu + ((ub.u >> 16) & 1u)) & 0xFFFF0000u;
  return ra | rb;
}
__device__ __forceinline__ uint2 pack4(f32x4 v) {
  uint2 o; o.x = pack2(v[0], v[1]); o.y = pack2(v[2], v[3]); return o;
}
__device__ __forceinline__ unsigned short f2b(float f) {
  union { float f; unsigned int u; } c; c.f = f;
  return (unsigned short)((c.u + 0x7FFFu + ((c.u >> 16) & 1u)) >> 16);
}

// K0: fp32 weights -> bf16, [Wq|Wk|Wv|Wp] each 256x256.
__global__ __launch_bounds__(256) void k0_cvt(const float* __restrict__ w0,
                                              const float* __restrict__ w1,
                                              const float* __restrict__ w2,
                                              const float* __restrict__ w3,
                                              unsigned short* __restrict__ dst) {
  int idx = blockIdx.x * 256 + threadIdx.x;
  const float* s = (blockIdx.y == 0) ? w0 : (blockIdx.y == 1) ? w1 : (blockIdx.y == 2) ? w2 : w3;
  dst[blockIdx.y * 65536 + idx] = f2b(s[idx]);
}

// KA: one window per 512-thread block; wave wv owns head wv entirely (wave-private
// attention, no barriers between QKV/S/softmax/PV). 3 barriers total.
// Gather + LayerNorm fused in the staging phase: wave wv owns tokens l = wv*8..wv*8+7
// (all share n = nbb*8+wv, so source rows are wave-uniform; no tok_off dependency).
__global__ __launch_bounds__(512, 2) void ka_fused(
    const unsigned short* __restrict__ Wall,
    const float* __restrict__ ln_g, const float* __restrict__ ln_b,
    const int* __restrict__ pn, const int* __restrict__ pt,
    const float* __restrict__ bq, const float* __restrict__ bk,
    const float* __restrict__ bv, const float* __restrict__ bp,
    const float* __restrict__ inpt, float* __restrict__ out) {
  extern __shared__ unsigned short lds[];
  int* tok_off = (int*)(lds + LDS_US);

  const int tid = threadIdx.x;
  const int wv = tid >> 6, lane = tid & 63, quad = lane >> 4, l15 = lane & 15;
  const int w = blockIdx.x;
  const int b = w >> 9, nbb = (w >> 6) & 7, tbb = w & 63;
  const f32x4 z4 = {0.f, 0.f, 0.f, 0.f};

  if (tid < 64) {
    const int n = (nbb << 3) + (tid >> 3), t = (tbb << 3) + (tid & 7);
    tok_off[tid] = (((b << 6) + pn[(b << 6) + n]) * 512 + pt[(b << 9) + t]) * 256;
  }

  // ---- fused gather + LayerNorm -> bf16 X tile rows [64][264] ----
  {
    const int n = (nbb << 3) + wv;
    const int spn = pn[(b << 6) + n];
    const float* rowbase = inpt + (size_t)((b << 6) + spn) * 512 * 256;
    const float4 gg = ((const float4*)ln_g)[lane];
    const float4 bb = ((const float4*)ln_b)[lane];
    float4 v[8];
    #pragma unroll
    for (int i = 0; i < 8; ++i) {
      const int spt = pt[(b << 9) + (tbb << 3) + i];
      v[i] = ((const float4*)(rowbase + (size_t)spt * 256))[lane];
    }
    #pragma unroll
    for (int i = 0; i < 8; ++i) {
      float s = v[i].x + v[i].y + v[i].z + v[i].w;
      float ss = v[i].x * v[i].x + v[i].y * v[i].y + v[i].z * v[i].z + v[i].w * v[i].w;
      #pragma unroll
      for (int m = 1; m < 64; m <<= 1) { s += __shfl_xor(s, m); ss += __shfl_xor(ss, m); }
      const float mean = s * (1.0f / 256.0f);
      const float rs = rsqrtf(ss * (1.0f / 256.0f) - mean * mean + EPS_);
      ushort4 o;
      o.x = f2b((v[i].x - mean) * rs * gg.x + bb.x);
      o.y = f2b((v[i].y - mean) * rs * gg.y + bb.y);
      o.z = f2b((v[i].z - mean) * rs * gg.z + bb.z);
      o.w = f2b((v[i].w - mean) * rs * gg.w + bb.w);
      ((ushort4*)(lds + (wv * 8 + i) * XS))[lane] = o;
    }
  }
  __syncthreads();

  const unsigned short* Wq = Wall;
  const unsigned short* Wk = Wall + 65536;
  const unsigned short* Wv_ = Wall + 131072;
  const unsigned short* Wp = Wall + 196608;
  unsigned short* chunk = lds + SCB + wv * CHUNK;
  const int h = wv;

  // ---- QKV for head h: Q^T,K^T = W·X^T (A=W rows=ch, B=X rows=tok); V = X·Wv^T ----
  f32x4 qa[2][4], ka_[2][4], va[4][2];
  #pragma unroll
  for (int m2 = 0; m2 < 2; ++m2)
    #pragma unroll
    for (int nt = 0; nt < 4; ++nt) { qa[m2][nt] = z4; ka_[m2][nt] = z4; }
  #pragma unroll
  for (int mt = 0; mt < 4; ++mt)
    #pragma unroll
    for (int m2 = 0; m2 < 2; ++m2) va[mt][m2] = z4;

  #pragma unroll
  for (int ks = 0; ks < 8; ++ks) {
    bf16x8 bx[4];
    #pragma unroll
    for (int nt = 0; nt < 4; ++nt)
      bx[nt] = *(const bf16x8*)(lds + (nt * 16 + l15) * XS + ks * 32 + quad * 8);
    #pragma unroll
    for (int m2 = 0; m2 < 2; ++m2) {
      const int wrow = (h * 32 + m2 * 16 + l15) * 256 + ks * 32 + quad * 8;
      bf16x8 wq8 = *(const bf16x8*)(Wq + wrow);
      bf16x8 wk8 = *(const bf16x8*)(Wk + wrow);
      bf16x8 wv8 = *(const bf16x8*)(Wv_ + wrow);
      #pragma unroll
      for (int nt = 0; nt < 4; ++nt) {
        qa[m2][nt] = __builtin_amdgcn_mfma_f32_16x16x32_bf16(wq8, bx[nt], qa[m2][nt], 0, 0, 0);
        ka_[m2][nt] = __builtin_amdgcn_mfma_f32_16x16x32_bf16(wk8, bx[nt], ka_[m2][nt], 0, 0, 0);
        va[nt][m2] = __builtin_amdgcn_mfma_f32_16x16x32_bf16(bx[nt], wv8, va[nt][m2], 0, 0, 0);
      }
    }
  }

  // stores: q/k rows=tok (col=l15), packed over ch; vT rows=ch, packed over tok
  #pragma unroll
  for (int m2 = 0; m2 < 2; ++m2) {
    float4 bq4 = ((const float4*)(bq + h * 32 + m2 * 16))[quad];
    float4 bk4 = ((const float4*)(bk + h * 32 + m2 * 16))[quad];
    #pragma unroll
    for (int nt = 0; nt < 4; ++nt) {
      f32x4 qv, kv;
      qv[0] = (qa[m2][nt][0] + bq4.x) * QSC; kv[0] = ka_[m2][nt][0] + bk4.x;
      qv[1] = (qa[m2][nt][1] + bq4.y) * QSC; kv[1] = ka_[m2][nt][1] + bk4.y;
      qv[2] = (qa[m2][nt][2] + bq4.z) * QSC; kv[2] = ka_[m2][nt][2] + bk4.z;
      qv[3] = (qa[m2][nt][3] + bq4.w) * QSC; kv[3] = ka_[m2][nt][3] + bk4.w;
      *(uint2*)(chunk + (nt * 16 + l15) * QSTR + m2 * 16 + quad * 4) = pack4(qv);
      *(uint2*)(chunk + KOFF + (nt * 16 + l15) * QSTR + m2 * 16 + quad * 4) = pack4(kv);
    }
    const float bvv = bv[h * 32 + m2 * 16 + l15];
    #pragma unroll
    for (int mt = 0; mt < 4; ++mt) {
      f32x4 vv;
      vv[0] = va[mt][m2][0] + bvv; vv[1] = va[mt][m2][1] + bvv;
      vv[2] = va[mt][m2][2] + bvv; vv[3] = va[mt][m2][3] + bvv;
      *(uint2*)(chunk + VTOFF + (m2 * 16 + l15) * VSTR + mt * 16 + quad * 4) = pack4(vv);
    }
  }

  // ---- S^T = k·q^T (col=qtok, row=ktok), K=32 ----
  bf16x8 qf[4], kf[4];
  #pragma unroll
  for (int i = 0; i < 4; ++i) {
    qf[i] = *(const bf16x8*)(chunk + (i * 16 + l15) * QSTR + quad * 8);
    kf[i] = *(const bf16x8*)(chunk + KOFF + (i * 16 + l15) * QSTR + quad * 8);
  }
  f32x4 st[4][4];  // [mtk][ntq]
  #pragma unroll
  for (int mtk = 0; mtk < 4; ++mtk)
    #pragma unroll
    for (int ntq = 0; ntq < 4; ++ntq)
      st[mtk][ntq] = __builtin_amdgcn_mfma_f32_16x16x32_bf16(kf[mtk], qf[ntq], z4, 0, 0, 0);

  // softmax over ktok (VALU sums + 2 swizzles per qtok-tile; exp2, no max-subtract)
  float inv[4];
  #pragma unroll
  for (int ntq = 0; ntq < 4; ++ntq) {
    float tot = 0.f;
    #pragma unroll
    for (int mtk = 0; mtk < 4; ++mtk)
      #pragma unroll
      for (int r = 0; r < 4; ++r) {
        const float e = __builtin_amdgcn_exp2f(st[mtk][ntq][r]);
        st[mtk][ntq][r] = e; tot += e;
      }
    tot += __shfl_xor(tot, 16);
    tot += __shfl_xor(tot, 32);
    inv[ntq] = 1.0f / tot;
  }
  // P[qtok][ktok] (overlays q+k region; qf/kf already in regs)
  #pragma unroll
  for (int ntq = 0; ntq < 4; ++ntq)
    #pragma unroll
    for (int mtk = 0; mtk < 4; ++mtk) {
      f32x4 pv;
      pv[0] = st[mtk][ntq][0] * inv[ntq]; pv[1] = st[mtk][ntq][1] * inv[ntq];
      pv[2] = st[mtk][ntq][2] * inv[ntq]; pv[3] = st[mtk][ntq][3] * inv[ntq];
      *(uint2*)(chunk + (ntq * 16 + l15) * PSTR + mtk * 16 + quad * 4) = pack4(pv);
    }

  // ---- O^T = V^T·P^T (A=vT rows=ch, B=P rows=qtok), K=64 ----
  f32x4 oa[2][4];
  #pragma unroll
  for (int m2 = 0; m2 < 2; ++m2)
    #pragma unroll
    for (int ntq = 0; ntq < 4; ++ntq) oa[m2][ntq] = z4;
  #pragma unroll
  for (int kk = 0; kk < 2; ++kk) {
    bf16x8 pb[4], vf[2];
    #pragma unroll
    for (int ntq = 0; ntq < 4; ++ntq)
      pb[ntq] = *(const bf16x8*)(chunk + (ntq * 16 + l15) * PSTR + kk * 32 + quad * 8);
    #pragma unroll
    for (int m2 = 0; m2 < 2; ++m2)
      vf[m2] = *(const bf16x8*)(chunk + VTOFF + (m2 * 16 + l15) * VSTR + kk * 32 + quad * 8);
    #pragma unroll
    for (int m2 = 0; m2 < 2; ++m2)
      #pragma unroll
      for (int ntq = 0; ntq < 4; ++ntq)
        oa[m2][ntq] = __builtin_amdgcn_mfma_f32_16x16x32_bf16(vf[m2], pb[ntq], oa[m2][ntq], 0, 0, 0);
  }
  uint2 opk[2][4];
  #pragma unroll
  for (int m2 = 0; m2 < 2; ++m2)
    #pragma unroll
    for (int ntq = 0; ntq < 4; ++ntq) opk[m2][ntq] = pack4(oa[m2][ntq]);

  __syncthreads();  // all waves done reading X
  #pragma unroll
  for (int m2 = 0; m2 < 2; ++m2)
    #pragma unroll
    for (int ntq = 0; ntq < 4; ++ntq)
      *(uint2*)(lds + (ntq * 16 + l15) * XS + h * 32 + m2 * 16 + quad * 4) = opk[m2][ntq];
  __syncthreads();  // obuf ready

  // ---- proj^T = Wp·O^T : wave owns out-channels [wv*32, wv*32+32) ----
  f32x4 pacc[2][4];
  #pragma unroll
  for (int m2 = 0; m2 < 2; ++m2)
    #pragma unroll
    for (int nto = 0; nto < 4; ++nto) pacc[m2][nto] = z4;
  #pragma unroll
  for (int ks = 0; ks < 8; ++ks) {
    bf16x8 ob[4];
    #pragma unroll
    for (int nto = 0; nto < 4; ++nto)
      ob[nto] = *(const bf16x8*)(lds + (nto * 16 + l15) * XS + ks * 32 + quad * 8);
    #pragma unroll
    for (int m2 = 0; m2 < 2; ++m2) {
      bf16x8 wp8 = *(const bf16x8*)(Wp + (wv * 32 + m2 * 16 + l15) * 256 + ks * 32 + quad * 8);
      #pragma unroll
      for (int nto = 0; nto < 4; ++nto)
        pacc[m2][nto] = __builtin_amdgcn_mfma_f32_16x16x32_bf16(wp8, ob[nto], pacc[m2][nto], 0, 0, 0);
    }
  }

  // ---- epilogue: +bp, residual, float4 scatter (col=tok, row=och) ----
  #pragma unroll
  for (int m2 = 0; m2 < 2; ++m2) {
    float4 bp4 = ((const float4*)(bp + wv * 32 + m2 * 16))[quad];
    #pragma unroll
    for (int nto = 0; nto < 4; ++nto) {
      const int tok = nto * 16 + l15;
      const int off = tok_off[tok] + wv * 32 + m2 * 16 + quad * 4;
      float4 iv = *(const float4*)(inpt + off);
      float4 o;
      o.x = iv.x + pacc[m2][nto][0] + bp4.x;
      o.y = iv.y + pacc[m2][nto][1] + bp4.y;
      o.z = iv.z + pacc[m2][nto][2] + bp4.z;
      o.w = iv.w + pacc[m2][nto][3] + bp4.w;
      *(float4*)(out + off) = o;
    }
  }
}

extern "C" void kernel_launch(void* const* d_in, const int* in_sizes, int n_in,
                              void* d_out, int out_size, void* d_ws, size_t ws_size,
                              hipStream_t stream) {
  const float* inpt = (const float*)d_in[0];
  const int* perm_n = (const int*)d_in[1];
  const int* perm_t = (const int*)d_in[2];
  const float* ln_g = (const float*)d_in[3];
  const float* ln_b = (const float*)d_in[4];
  const float* Wq = (const float*)d_in[5];
  const float* bq = (const float*)d_in[6];
  const float* Wk = (const float*)d_in[7];
  const float* bk = (const float*)d_in[8];
  const float* Wv = (const float*)d_in[9];
  const float* bv = (const float*)d_in[10];
  const float* Wp = (const float*)d_in[11];
  const float* bp = (const float*)d_in[12];
  float* out = (float*)d_out;

  // ws: Wall (512 KiB) only — Xg intermediate eliminated (LN+gather fused into ka)
  unsigned short* Wall = (unsigned short*)d_ws;

  (void)hipFuncSetAttribute((const void*)ka_fused,
                            hipFuncAttributeMaxDynamicSharedMemorySize, LDS_BYTES);

  k0_cvt<<<dim3(256, 4), 256, 0, stream>>>(Wq, Wk, Wv, Wp, Wall);
  ka_fused<<<2048, 512, LDS_BYTES, stream>>>(Wall, ln_g, ln_b, perm_n, perm_t,
                                             bq, bk, bv, bp, inpt, out);
}